// Round 1
// 711.361 us; speedup vs baseline: 1.0719x; 1.0719x over previous
//
#include <hip/hip_runtime.h>
#include <hip/hip_bf16.h>
#include <math.h>

#define N_NODES 400000
#define DIM 256
#define NSEG 2048

typedef unsigned short u16;
typedef float floatx4 __attribute__((ext_vector_type(4)));
typedef __bf16 bf16x8 __attribute__((ext_vector_type(8)));
typedef _Float16 f16x4 __attribute__((ext_vector_type(4)));
typedef _Float16 f16x8 __attribute__((ext_vector_type(8)));

__device__ __forceinline__ u16 f2bf(float f) {
    __hip_bfloat16 h = __float2bfloat16(f);
    return *reinterpret_cast<u16*>(&h);
}
__device__ __forceinline__ float sigf(float x) { return 1.0f / (1.0f + __expf(-x)); }

// ---------------- segment starts from sorted index (int32/int64 auto-detect) ----------------
__global__ void seg_starts_kernel(const int* __restrict__ idx32, int* __restrict__ seg) {
    int n = blockIdx.x * blockDim.x + threadIdx.x;
    if (n >= N_NODES) return;
    const bool is64 = (idx32[N_NODES - 1] == 0);
    int cur  = is64 ? idx32[2 * n] : idx32[n];
    int prev = (n == 0) ? -1 : (is64 ? idx32[2 * (n - 1)] : idx32[n - 1]);
    cur  = min(max(cur, -1), NSEG - 1);
    prev = min(max(prev, -1), NSEG - 1);
    for (int s = prev + 1; s <= cur; ++s) seg[s] = n;
    if (n == N_NODES - 1) {
        for (int s = cur + 1; s <= NSEG; ++s) seg[s] = N_NODES;
    }
}

// ---------------- weight prep: Wc = [Wih[:,0:256]+Whh | Wih[:,256:512]] (bf16), Wp -> bf16 ----
__global__ void prep_weights_kernel(const float* __restrict__ Wih, const float* __restrict__ Whh,
                                    const float* __restrict__ Wp,
                                    u16* __restrict__ Wc, u16* __restrict__ WpB) {
    int idx = blockIdx.x * blockDim.x + threadIdx.x;
    if (idx < 1024 * 512) {
        int j = idx >> 9, k = idx & 511;
        float v = Wih[(size_t)j * 512 + k];
        if (k < 256) v += Whh[(size_t)j * 256 + k];
        Wc[idx] = f2bf(v);
    }
    if (idx < 256 * 512) WpB[idx] = f2bf(Wp[idx]);
}

// ---------------- t=0 LSTM: all states zero -> gates = bih + bhh ----------------
__global__ void lstm_bias_kernel(const float* __restrict__ bih, const float* __restrict__ bhh,
                                 float* __restrict__ c, float* __restrict__ h,
                                 u16* __restrict__ A) {
    int idx = blockIdx.x * blockDim.x + threadIdx.x;
    if (idx >= NSEG * DIM) return;
    int b = idx >> 8, d = idx & 255;
    float gi = bih[d]       + bhh[d];
    float gg = bih[d + 512] + bhh[d + 512];
    float go = bih[d + 768] + bhh[d + 768];
    float cn = sigf(gi) * tanhf(gg);
    float hn = sigf(go) * tanhf(cn);
    c[idx] = cn;
    h[idx] = hn;
    A[(size_t)b * 512 + d] = f2bf(hn);
}

// ---------------- LSTM pointwise from fp32 gates ----------------
__global__ void lstm_pw_kernel(const float* __restrict__ gates,
                               const float* __restrict__ bih, const float* __restrict__ bhh,
                               float* __restrict__ c, float* __restrict__ h,
                               u16* __restrict__ A) {
    int idx = blockIdx.x * blockDim.x + threadIdx.x;
    if (idx >= NSEG * DIM) return;
    int b = idx >> 8, d = idx & 255;
    const float* g = gates + (size_t)b * 1024;
    float gi = g[d]       + bih[d]       + bhh[d];
    float gf = g[d + 256] + bih[d + 256] + bhh[d + 256];
    float gg = g[d + 512] + bih[d + 512] + bhh[d + 512];
    float go = g[d + 768] + bih[d + 768] + bhh[d + 768];
    float cn = sigf(gf) * c[idx] + sigf(gi) * tanhf(gg);
    float hn = sigf(go) * tanhf(cn);
    c[idx] = cn;
    h[idx] = hn;
    A[(size_t)b * 512 + d] = f2bf(hn);
}

// ---------------- t=0 attention (fp32 x) fused with x -> fp16 conversion ----------------
// one block per segment; wave w handles nodes s0+w, s0+w+4, ...; lane owns dims 4*lane..4*lane+3
__global__ __launch_bounds__(256) void attn0_kernel(const float* __restrict__ x,
                                                    const int* __restrict__ seg,
                                                    const float* __restrict__ h,
                                                    u16* __restrict__ A,
                                                    _Float16* __restrict__ xh) {
    const int b = blockIdx.x;
    const int tid = threadIdx.x;
    const int wave = tid >> 6, lane = tid & 63;
    int s0 = seg[b], s1 = seg[b + 1];
    s0 = max(s0, 0);
    s1 = min(s1, N_NODES);

    if (s1 <= s0) {
        A[(size_t)b * 512 + 256 + tid] = (u16)0;
        return;
    }

    __shared__ float sm[4], sz[4];
    __shared__ float sr[4][256];

    const float4 qv = *(const float4*)(h + (size_t)b * 256 + lane * 4);

    float m = -INFINITY, z = 0.f;
    float r0 = 0.f, r1 = 0.f, r2 = 0.f, r3 = 0.f;

    for (int n = s0 + wave; n < s1; n += 4) {
        const float4 xv = *(const float4*)(x + (size_t)n * 256 + lane * 4);
        // fp16 cache write (each node written exactly once across the grid)
        f16x4 hv;
        hv[0] = (_Float16)xv.x; hv[1] = (_Float16)xv.y;
        hv[2] = (_Float16)xv.z; hv[3] = (_Float16)xv.w;
        *(f16x4*)(xh + (size_t)n * 256 + lane * 4) = hv;

        float e = xv.x * qv.x + xv.y * qv.y + xv.z * qv.z + xv.w * qv.w;
        e += __shfl_xor(e, 1);
        e += __shfl_xor(e, 2);
        e += __shfl_xor(e, 4);
        e += __shfl_xor(e, 8);
        e += __shfl_xor(e, 16);
        e += __shfl_xor(e, 32);
        float nm = fmaxf(m, e);
        float corr = __expf(m - nm);
        float p = __expf(e - nm);
        z = z * corr + p;
        r0 = r0 * corr + p * xv.x;
        r1 = r1 * corr + p * xv.y;
        r2 = r2 * corr + p * xv.z;
        r3 = r3 * corr + p * xv.w;
        m = nm;
    }

    if (lane == 0) { sm[wave] = m; sz[wave] = z; }
    sr[wave][lane * 4 + 0] = r0;
    sr[wave][lane * 4 + 1] = r1;
    sr[wave][lane * 4 + 2] = r2;
    sr[wave][lane * 4 + 3] = r3;
    __syncthreads();

    float M = fmaxf(fmaxf(sm[0], sm[1]), fmaxf(sm[2], sm[3]));
    float zz = 0.f, rr = 0.f;
    for (int w = 0; w < 4; ++w) {
        float cw = __expf(sm[w] - M);
        zz += cw * sz[w];
        rr += cw * sr[w][tid];
    }
    A[(size_t)b * 512 + 256 + tid] = f2bf(rr / zz);
}

// ---------------- t=1,2 attention on fp16 x: 2 nodes/wave/iter, prefetch ----------------
// half-wave (32 lanes) owns one node: lane l32 holds dims 8*l32..8*l32+7 (16B load)
// 8 node-streams per block (4 waves x 2 halves), merged in LDS at the end
__global__ __launch_bounds__(256) void attn_h_kernel(const _Float16* __restrict__ xh,
                                                     const int* __restrict__ seg,
                                                     const float* __restrict__ h,
                                                     u16* __restrict__ A) {
    const int b = blockIdx.x;
    const int tid = threadIdx.x;
    const int wave = tid >> 6, lane = tid & 63;
    const int sub = lane >> 5;          // half-wave id
    const int l32 = lane & 31;
    const int hs = wave * 2 + sub;      // node-stream id 0..7

    int s0 = seg[b], s1 = seg[b + 1];
    s0 = max(s0, 0);
    s1 = min(s1, N_NODES);

    if (s1 <= s0) {
        A[(size_t)b * 512 + 256 + tid] = (u16)0;
        return;
    }

    __shared__ float sm[8], sz[8];
    __shared__ float sr[8][256];

    float q[8];
    {
        const float4 q0 = *(const float4*)(h + (size_t)b * 256 + l32 * 8);
        const float4 q1 = *(const float4*)(h + (size_t)b * 256 + l32 * 8 + 4);
        q[0] = q0.x; q[1] = q0.y; q[2] = q0.z; q[3] = q0.w;
        q[4] = q1.x; q[5] = q1.y; q[6] = q1.z; q[7] = q1.w;
    }

    float m = -INFINITY, z = 0.f;
    float r[8] = {};

    int n = s0 + hs;
    f16x8 cur = {};
    if (n < s1) cur = *(const f16x8*)(xh + (size_t)n * 256 + l32 * 8);

    while (n < s1) {
        const int n2 = n + 8;
        f16x8 nxt = {};
        if (n2 < s1) nxt = *(const f16x8*)(xh + (size_t)n2 * 256 + l32 * 8);

        float xf[8];
        float e = 0.f;
        #pragma unroll
        for (int j = 0; j < 8; ++j) { xf[j] = (float)cur[j]; e += xf[j] * q[j]; }
        // reduce across the 32-lane half-wave
        e += __shfl_xor(e, 1);
        e += __shfl_xor(e, 2);
        e += __shfl_xor(e, 4);
        e += __shfl_xor(e, 8);
        e += __shfl_xor(e, 16);

        float nm = fmaxf(m, e);
        float corr = __expf(m - nm);
        float p = __expf(e - nm);
        z = z * corr + p;
        #pragma unroll
        for (int j = 0; j < 8; ++j) r[j] = r[j] * corr + p * xf[j];
        m = nm;

        cur = nxt;
        n = n2;
    }

    if (l32 == 0) { sm[hs] = m; sz[hs] = z; }
    #pragma unroll
    for (int j = 0; j < 8; ++j) sr[hs][l32 * 8 + j] = r[j];
    __syncthreads();

    // merge 8 streams; thread t handles dim t
    float M = sm[0];
    #pragma unroll
    for (int w = 1; w < 8; ++w) M = fmaxf(M, sm[w]);
    float zz = 0.f, rr = 0.f;
    #pragma unroll
    for (int w = 0; w < 8; ++w) {
        float cw = __expf(sm[w] - M);   // empty stream: exp(-inf)=0
        zz += cw * sz[w];
        rr += cw * sr[w][tid];
    }
    A[(size_t)b * 512 + 256 + tid] = f2bf(rr / zz);
}

// ---------------- MFMA bf16 GEMM: C[M,N] = A[M,K] @ W[N,K]^T (+bias), fp32 out ----------
template<bool BIAS>
__global__ __launch_bounds__(256) void gemm_bt_kernel(const u16* __restrict__ Ag,
                                                      const u16* __restrict__ Wg,
                                                      const float* __restrict__ bias,
                                                      float* __restrict__ C,
                                                      int M, int N, int K) {
    __shared__ __align__(16) u16 As[64][40];
    __shared__ __align__(16) u16 Ws[64][40];

    const int tid = threadIdx.x;
    const int bm = blockIdx.x * 64;
    const int bn = blockIdx.y * 64;
    const int wave = tid >> 6, lane = tid & 63;
    const int wm = (wave & 1) * 32;
    const int wn = (wave >> 1) * 32;
    const int quad = lane >> 4;
    const int r16 = lane & 15;

    const int lrow = tid >> 2;
    const int lcol = (tid & 3) * 8;

    floatx4 acc[2][2] = {};

    for (int k0 = 0; k0 < K; k0 += 32) {
        *(uint4*)&As[lrow][lcol] = *(const uint4*)&Ag[(size_t)(bm + lrow) * K + k0 + lcol];
        *(uint4*)&Ws[lrow][lcol] = *(const uint4*)&Wg[(size_t)(bn + lrow) * K + k0 + lcol];
        __syncthreads();
        bf16x8 af0 = *(const bf16x8*)&As[wm + r16][quad * 8];
        bf16x8 af1 = *(const bf16x8*)&As[wm + 16 + r16][quad * 8];
        bf16x8 wf0 = *(const bf16x8*)&Ws[wn + r16][quad * 8];
        bf16x8 wf1 = *(const bf16x8*)&Ws[wn + 16 + r16][quad * 8];
        acc[0][0] = __builtin_amdgcn_mfma_f32_16x16x32_bf16(af0, wf0, acc[0][0], 0, 0, 0);
        acc[0][1] = __builtin_amdgcn_mfma_f32_16x16x32_bf16(af0, wf1, acc[0][1], 0, 0, 0);
        acc[1][0] = __builtin_amdgcn_mfma_f32_16x16x32_bf16(af1, wf0, acc[1][0], 0, 0, 0);
        acc[1][1] = __builtin_amdgcn_mfma_f32_16x16x32_bf16(af1, wf1, acc[1][1], 0, 0, 0);
        __syncthreads();
    }

    for (int tm = 0; tm < 2; ++tm)
        for (int tn = 0; tn < 2; ++tn)
            for (int j = 0; j < 4; ++j) {
                int row = bm + wm + tm * 16 + quad * 4 + j;
                int col = bn + wn + tn * 16 + r16;
                float v = acc[tm][tn][j];
                if (BIAS) v += bias[col];
                C[(size_t)row * N + col] = v;
            }
}

extern "C" void kernel_launch(void* const* d_in, const int* in_sizes, int n_in,
                              void* d_out, int out_size, void* d_ws, size_t ws_size,
                              hipStream_t stream) {
    const float* x   = (const float*)d_in[0];
    const int*   idx = (const int*)d_in[1];
    const float* Wih = (const float*)d_in[2];
    const float* Whh = (const float*)d_in[3];
    const float* bih = (const float*)d_in[4];
    const float* bhh = (const float*)d_in[5];
    const float* Wp  = (const float*)d_in[6];
    const float* bp  = (const float*)d_in[7];
    float* out = (float*)d_out;

    char* w = (char*)d_ws;
    int*   seg     = (int*)w;        w += 16384;
    u16*   A       = (u16*)w;        w += (size_t)NSEG * 512 * 2;       // 2 MB  [h | r] bf16
    u16*   Wc      = (u16*)w;        w += (size_t)1024 * 512 * 2;       // 1 MB
    u16*   WpB     = (u16*)w;        w += (size_t)256 * 512 * 2;        // 256 KB
    float* h_f32   = (float*)w;      w += (size_t)NSEG * DIM * 4;       // 2 MB
    float* c_f32   = (float*)w;      w += (size_t)NSEG * DIM * 4;       // 2 MB
    float* gates   = (float*)w;      w += (size_t)NSEG * 1024 * 4;      // 8 MB
    _Float16* xh   = (_Float16*)w;   w += (size_t)N_NODES * DIM * 2;    // 204.8 MB fp16 x cache

    seg_starts_kernel<<<(N_NODES + 255) / 256, 256, 0, stream>>>(idx, seg);
    prep_weights_kernel<<<(1024 * 512 + 255) / 256, 256, 0, stream>>>(Wih, Whh, Wp, Wc, WpB);

    // t = 0: states are zero -> bias-only LSTM; attention also emits the fp16 x cache
    lstm_bias_kernel<<<(NSEG * DIM + 255) / 256, 256, 0, stream>>>(bih, bhh, c_f32, h_f32, A);
    attn0_kernel<<<NSEG, 256, 0, stream>>>(x, seg, h_f32, A, xh);

    // t = 1, 2: attention reads the fp16 cache (L3-resident: 204.8 MB < 256 MB)
    for (int t = 1; t < 3; ++t) {
        gemm_bt_kernel<false><<<dim3(2048 / 64, 1024 / 64), 256, 0, stream>>>(
            A, Wc, nullptr, gates, 2048, 1024, 512);
        lstm_pw_kernel<<<(NSEG * DIM + 255) / 256, 256, 0, stream>>>(gates, bih, bhh,
                                                                     c_f32, h_f32, A);
        attn_h_kernel<<<NSEG, 256, 0, stream>>>(xh, seg, h_f32, A);
    }

    // out = q_star @ Wp^T + bp
    gemm_bt_kernel<true><<<dim3(2048 / 64, 256 / 64), 256, 0, stream>>>(
        A, WpB, bp, out, 2048, 256, 512);
}